// Round 10
// baseline (374.822 us; speedup 1.0000x reference)
//
#include <hip/hip_runtime.h>
#include <hip/hip_bf16.h>
#include <cstdint>

typedef __attribute__((ext_vector_type(8))) short short8;
typedef __attribute__((ext_vector_type(4))) float f32x4;
typedef __attribute__((ext_vector_type(16))) float f32x16;
typedef unsigned short ushort_t;

#define MM 8192
#define NN 4096
#define KK 4096

#define BM 128
#define BN 128
#define BK 64
#define NT (KK / BK)  // 64 K-tiles

#define MFMA_BF16 __builtin_amdgcn_mfma_f32_16x16x32_bf16
#define MFMA32 __builtin_amdgcn_mfma_f32_32x32x16_bf16

// fp32 -> bf16 round-to-nearest-even (inputs are finite)
__device__ __forceinline__ ushort_t f2bf(float f) {
  uint32_t u = __builtin_bit_cast(uint32_t, f);
  u = (u + 0x7FFFu + ((u >> 16) & 1u)) >> 16;
  return (ushort_t)u;
}

// fused activation chain: leaky_relu -> +y -> mish -> hardswish + 0.5
__device__ __forceinline__ float epilogue(float v, float yv) {
  v = fmaxf(v, 0.01f * v);  // leaky relu
  v += yv;
  const float vc = fminf(v, 15.f);
  const float t = __builtin_amdgcn_exp2f(vc * 1.44269504f);  // e^vc
  const float d = t * t + 2.f * t;
  const float mi = v * d * __builtin_amdgcn_rcpf(d + 2.f);   // mish
  const float r6 = fminf(fmaxf(mi + 3.f, 0.f), 6.f);
  return mi * r6 * (1.f / 6.f) + 0.5f;                       // hardswish + 0.5
}

// async 16B global->LDS (LDS dest is wave-uniform base + lane*16)
__device__ __forceinline__ void gload_lds16(const void* g, void* l) {
  __builtin_amdgcn_global_load_lds(
      (const __attribute__((address_space(1))) unsigned int*)g,
      (__attribute__((address_space(3))) unsigned int*)l, 16, 0, 0);
}

#define CVT_BLOCKS ((MM * KK) / (256 * 8))      // 16384
#define WT_BLOCKS ((NN / 32) * (KK / 32))       // 16384

// ---------------- merged prep: X convert (bid<CVT_BLOCKS) + W transpose ----------------
template <int DO_X>
__global__ void prep_kernel(const float* __restrict__ X, ushort_t* __restrict__ XB,
                            const float* __restrict__ W, ushort_t* __restrict__ WT) {
  __shared__ float t[32][33];
  const int bid = blockIdx.x;
  const int tid = threadIdx.x;
  if (DO_X && bid < CVT_BLOCKS) {
    const size_t i = ((size_t)bid * 256 + tid) * 8;
    f32x4 v0 = __builtin_nontemporal_load(reinterpret_cast<const f32x4*>(&X[i]));
    f32x4 v1 = __builtin_nontemporal_load(reinterpret_cast<const f32x4*>(&X[i + 4]));
    short8 o;
    o[0] = (short)f2bf(v0[0]); o[1] = (short)f2bf(v0[1]);
    o[2] = (short)f2bf(v0[2]); o[3] = (short)f2bf(v0[3]);
    o[4] = (short)f2bf(v1[0]); o[5] = (short)f2bf(v1[1]);
    o[6] = (short)f2bf(v1[2]); o[7] = (short)f2bf(v1[3]);
    *reinterpret_cast<short8*>(&XB[i]) = o;
  } else {
    const int b2 = DO_X ? (bid - CVT_BLOCKS) : bid;
    const int n0 = (b2 & 127) * 32, k0 = (b2 >> 7) * 32;
    const int tx = tid & 31, ty = tid >> 5;  // 32 x 8
#pragma unroll
    for (int i = ty; i < 32; i += 8)
      t[i][tx] = __builtin_nontemporal_load(&W[(size_t)(k0 + i) * NN + n0 + tx]);
    __syncthreads();
#pragma unroll
    for (int i = ty; i < 32; i += 8)
      WT[(size_t)(n0 + i) * KK + k0 + tx] = f2bf(t[tx][i]);
  }
}

// -------- main fused GEMM: R0 champion structure + 32x32x16 MFMA (12% lower floor) -----
// R10. Six consecutive scheduling nulls on the 8-phase structure (R1-R3, R9)
// localize nothing; R0's 4-independent-blocks/CU structure has the session's
// best overlap (MfmaUtil 48.1%, 0 conflicts). Orthogonal lever: MFMA shape.
// m119: 32x32x16 = 2495 TF vs 16x16x32 = 2176 TF -> -12% MFMA floor at
// IDENTICAL LDS read bytes (per wave-tile: 16 b128 reads + 16 MFMA32 vs
// 16 reads + 32 MFMA16; matrix-issue slots halved too). Fragment maps are
// R5-verified on HW (passed refcheck). Everything else = R0 verbatim:
// 128^2 tile, 4 waves, single 32KB buffer, 4 blocks/CU, barrier-separated
// DMA (0 conflicts), slot-XOR swizzle (2-way max = free for the 32x32 read:
// quarter-wave = 16 lanes over 8 slot-groups), XCD block map, nt Y/O.
// No setprio (m190: hurts lockstep GEMM).
__global__ __launch_bounds__(256, 4) void gemm_bf16_r10(
    const ushort_t* __restrict__ XB, const ushort_t* __restrict__ WT,
    const float* __restrict__ Y, float* __restrict__ O) {
  __shared__ ushort_t As[BM * BK];  // 16 KB
  __shared__ ushort_t Bs[BN * BK];  // 16 KB

  // block map (R0): xcd = wg&7 owns 4-wide n-band (512 cols), m-fastest.
  // Per-XCD B working set = 4 panels = 4MB = L2-resident; A once via L3.
  const int wg = blockIdx.x;
  const int xcd = wg & 7;
  const int local = wg >> 3;           // 0..255
  const int bm0 = (local >> 2) * BM;   // 64 m-tiles, fastest
  const int bn0 = (xcd * 4 + (local & 3)) * BN;  // 4-wide n-band per XCD

  const int tid = threadIdx.x;
  const int lane = tid & 63;
  const int wid = tid >> 6;  // 0..3
  const int wm = (wid >> 1) * 64, wn = (wid & 1) * 64;

  // staging (R0 lane math): wave wid stages rows wid*32..+31 of A and B;
  // lane -> row wid*32 + j*8 + (lane>>3), dest slot lane&7 (linear),
  // src slot (lane&7)^(lane>>3) so LDS[row][s] = G[row][s^(row&7)]
  const int s_sub = lane >> 3;
  const int s_chunk = (lane & 7) ^ s_sub;
  uint32_t offA[4], offB[4];
#pragma unroll
  for (int j = 0; j < 4; ++j) {
    const int srow = wid * 32 + j * 8 + s_sub;
    offA[j] = (uint32_t)(bm0 + srow) * KK + s_chunk * 8;
    offB[j] = (uint32_t)(bn0 + srow) * KK + s_chunk * 8;
  }

  // 32x32 fragment read decomposition (R5-verified maps):
  // A frag (mf) row = wm + mf*32 + (lane&31); k-slot s = ks*2 + (lane>>5),
  // stored slot = s ^ (row&7) -> addr = row*64 + (s^l7)*8.
  const int l31 = lane & 31, kh = lane >> 5, l7 = lane & 7;
  const int aBase = (wm + l31) * BK;  // + mf*2048 + sl
  const int bBase = (wn + l31) * BK;  // + nf*2048 + sl
  const int sl0 = ((0 + kh) ^ l7) * 8;
  const int sl1 = ((2 + kh) ^ l7) * 8;
  const int sl2 = ((4 + kh) ^ l7) * 8;
  const int sl3 = ((6 + kh) ^ l7) * 8;

  f32x16 acc[2][2] = {};

#pragma unroll 1
  for (int kt = 0; kt < KK; kt += BK) {
    __syncthreads();  // previous compute done before overwrite
#pragma unroll
    for (int j = 0; j < 4; ++j) {
      gload_lds16(XB + offA[j] + kt, As + (wid * 4 + j) * 512);
      gload_lds16(WT + offB[j] + kt, Bs + (wid * 4 + j) * 512);
    }
    __syncthreads();  // barrier drains vmcnt -> tiles ready

#pragma unroll
    for (int ks = 0; ks < 4; ++ks) {
      const int sl = (ks == 0) ? sl0 : (ks == 1) ? sl1 : (ks == 2) ? sl2 : sl3;
      short8 a0 = *reinterpret_cast<const short8*>(&As[aBase + 0 * 2048 + sl]);
      short8 a1 = *reinterpret_cast<const short8*>(&As[aBase + 1 * 2048 + sl]);
      short8 b0 = *reinterpret_cast<const short8*>(&Bs[bBase + 0 * 2048 + sl]);
      short8 b1 = *reinterpret_cast<const short8*>(&Bs[bBase + 1 * 2048 + sl]);
      acc[0][0] = MFMA32(a0, b0, acc[0][0], 0, 0, 0);
      acc[0][1] = MFMA32(a0, b1, acc[0][1], 0, 0, 0);
      acc[1][0] = MFMA32(a1, b0, acc[1][0], 0, 0, 0);
      acc[1][1] = MFMA32(a1, b1, acc[1][1], 0, 0, 0);
    }
  }

  // epilogue: 32x32 C/D layout col=lane&31, row=(reg&3)+8*(reg>>2)+4*kh
  // [m74/m101; R5-verified end-to-end]
#pragma unroll
  for (int mf = 0; mf < 2; ++mf) {
#pragma unroll
    for (int nf = 0; nf < 2; ++nf) {
#pragma unroll
      for (int r = 0; r < 16; ++r) {
        const int grow = bm0 + wm + mf * 32 + (r & 3) + 8 * (r >> 2) + 4 * kh;
        const int gcol = bn0 + wn + nf * 32 + l31;
        const size_t idx = (size_t)grow * NN + gcol;
        const float yv = __builtin_nontemporal_load(&Y[idx]);
        __builtin_nontemporal_store(epilogue(acc[mf][nf][r], yv), &O[idx]);
      }
    }
  }
}

// ---------------- mid-tier (validated R1): reg-staged conversion GEMM ----------------
#define LDP 72
__global__ __launch_bounds__(256, 3) void gemm_fused(
    const float* __restrict__ X, const ushort_t* __restrict__ WT,
    const float* __restrict__ Y, float* __restrict__ O) {
  __shared__ ushort_t Asm[BM * LDP];
  __shared__ ushort_t Bsm[BN * LDP];

  const int nwg = (MM / BM) * (NN / BN);
  int wg = blockIdx.x;
  wg = (wg % 8) * (nwg / 8) + wg / 8;
  const int NTC = NN / BN;
  const int bm0 = (wg / NTC) * BM;
  const int bn0 = (wg % NTC) * BN;

  const int tid = threadIdx.x;
  const int lane = tid & 63;
  const int wid = tid >> 6;
  const int wm = (wid >> 1) * 64, wn = (wid & 1) * 64;
  const int lr = lane & 15, lg = lane >> 4;

  f32x4 acc[4][4] = {};

  const int arow = tid >> 2;
  const int ac = (tid & 3) * 4;
  const int brow = tid >> 1;
  const int bc0 = (tid & 1) * 32;

  for (int kt = 0; kt < KK; kt += BK) {
    __syncthreads();
#pragma unroll
    for (int p = 0; p < 2; ++p) {
      const int row = arow + p * 64;
      const float* src = &X[(size_t)(bm0 + row) * KK + kt];
#pragma unroll
      for (int j = 0; j < 4; ++j) {
        f32x4 v = *reinterpret_cast<const f32x4*>(&src[ac + j * 16]);
        uint2 packed;
        packed.x = (uint32_t)f2bf(v[0]) | ((uint32_t)f2bf(v[1]) << 16);
        packed.y = (uint32_t)f2bf(v[2]) | ((uint32_t)f2bf(v[3]) << 16);
        *reinterpret_cast<uint2*>(&Asm[row * LDP + ac + j * 16]) = packed;
      }
    }
    {
      const ushort_t* src = &WT[(size_t)(bn0 + brow) * KK + kt + bc0];
#pragma unroll
      for (int j = 0; j < 4; ++j) {
        short8 u = *reinterpret_cast<const short8*>(&src[j * 8]);
        *reinterpret_cast<short8*>(&Bsm[brow * LDP + bc0 + j * 8]) = u;
      }
    }
    __syncthreads();

#pragma unroll
    for (int ks = 0; ks < 2; ++ks) {
      short8 a[4], b[4];
#pragma unroll
      for (int i = 0; i < 4; ++i) {
        a[i] = *reinterpret_cast<const short8*>(&Asm[(wm + i * 16 + lr) * LDP + ks * 32 + lg * 8]);
        b[i] = *reinterpret_cast<const short8*>(&Bsm[(wn + i * 16 + lr) * LDP + ks * 32 + lg * 8]);
      }
#pragma unroll
      for (int i = 0; i < 4; ++i)
#pragma unroll
        for (int j = 0; j < 4; ++j)
          acc[i][j] = MFMA_BF16(a[i], b[j], acc[i][j], 0, 0, 0);
    }
  }

#pragma unroll
  for (int i = 0; i < 4; ++i) {
#pragma unroll
    for (int j = 0; j < 4; ++j) {
#pragma unroll
      for (int r = 0; r < 4; ++r) {
        const int grow = bm0 + wm + i * 16 + lg * 4 + r;
        const int gcol = bn0 + wn + j * 16 + lr;
        const size_t idx = (size_t)grow * NN + gcol;
        O[idx] = epilogue(acc[i][j][r], Y[idx]);
      }
    }
  }
}

// ---------------- naive fallback ----------------
__global__ void naive_fused(const float* __restrict__ X, const float* __restrict__ W,
                            const float* __restrict__ Y, float* __restrict__ O) {
  const int n0 = (blockIdx.x * 256 + threadIdx.x) * 4;
  const int m = blockIdx.y;
  f32x4 acc = {0.f, 0.f, 0.f, 0.f};
  const float* xr = &X[(size_t)m * KK];
  for (int k = 0; k < KK; ++k) {
    const float xv = xr[k];
    const f32x4 wv = *reinterpret_cast<const f32x4*>(&W[(size_t)k * NN + n0]);
    acc[0] += xv * wv[0];
    acc[1] += xv * wv[1];
    acc[2] += xv * wv[2];
    acc[3] += xv * wv[3];
  }
  const size_t idx = (size_t)m * NN + n0;
  O[idx + 0] = epilogue(acc[0], Y[idx + 0]);
  O[idx + 1] = epilogue(acc[1], Y[idx + 1]);
  O[idx + 2] = epilogue(acc[2], Y[idx + 2]);
  O[idx + 3] = epilogue(acc[3], Y[idx + 3]);
}

extern "C" void kernel_launch(void* const* d_in, const int* in_sizes, int n_in,
                              void* d_out, int out_size, void* d_ws, size_t ws_size,
                              hipStream_t stream) {
  const float* x = (const float*)d_in[0];
  const float* y = (const float*)d_in[1];
  const float* w = (const float*)d_in[2];
  float* out = (float*)d_out;

  const size_t xb_bytes = (size_t)MM * KK * sizeof(ushort_t);  // 67.1 MB
  const size_t wt_bytes = (size_t)NN * KK * sizeof(ushort_t);  // 33.5 MB

  if (ws_size >= xb_bytes + wt_bytes) {
    ushort_t* XB = (ushort_t*)d_ws;
    ushort_t* WT = (ushort_t*)((char*)d_ws + xb_bytes);
    hipLaunchKernelGGL((prep_kernel<1>), dim3(CVT_BLOCKS + WT_BLOCKS), dim3(256), 0, stream,
                       x, XB, w, WT);
    hipLaunchKernelGGL(gemm_bf16_r10, dim3((MM / BM) * (NN / BN)), dim3(256), 0, stream,
                       XB, WT, y, out);
  } else if (ws_size >= wt_bytes) {
    ushort_t* WT = (ushort_t*)d_ws;
    hipLaunchKernelGGL((prep_kernel<0>), dim3(WT_BLOCKS), dim3(256), 0, stream,
                       x, nullptr, w, WT);
    hipLaunchKernelGGL(gemm_fused, dim3((MM / BM) * (NN / BN)), dim3(256), 0, stream,
                       x, WT, y, out);
  } else {
    hipLaunchKernelGGL(naive_fused, dim3(NN / 1024, MM), dim3(256), 0, stream, x, w, y, out);
  }
}

// Round 11
// 326.170 us; speedup vs baseline: 1.1492x; 1.1492x over previous
//
#include <hip/hip_runtime.h>
#include <hip/hip_bf16.h>
#include <cstdint>

typedef __attribute__((ext_vector_type(8))) short short8;
typedef __attribute__((ext_vector_type(4))) float f32x4;
typedef unsigned short ushort_t;

#define MM 8192
#define NN 4096
#define KK 4096

#define BM 128
#define BN 128
#define BK 64
#define NT (KK / BK)  // 64 K-tiles

#define MFMA_BF16 __builtin_amdgcn_mfma_f32_16x16x32_bf16

// fp32 -> bf16 round-to-nearest-even (inputs are finite)
__device__ __forceinline__ ushort_t f2bf(float f) {
  uint32_t u = __builtin_bit_cast(uint32_t, f);
  u = (u + 0x7FFFu + ((u >> 16) & 1u)) >> 16;
  return (ushort_t)u;
}

// fused activation chain: leaky_relu -> +y -> mish -> hardswish + 0.5
__device__ __forceinline__ float epilogue(float v, float yv) {
  v = fmaxf(v, 0.01f * v);  // leaky relu
  v += yv;
  const float vc = fminf(v, 15.f);
  const float t = __builtin_amdgcn_exp2f(vc * 1.44269504f);  // e^vc
  const float d = t * t + 2.f * t;
  const float mi = v * d * __builtin_amdgcn_rcpf(d + 2.f);   // mish
  const float r6 = fminf(fmaxf(mi + 3.f, 0.f), 6.f);
  return mi * r6 * (1.f / 6.f) + 0.5f;                       // hardswish + 0.5
}

// async 16B global->LDS (LDS dest is wave-uniform base + lane*16)
__device__ __forceinline__ void gload_lds16(const void* g, void* l) {
  __builtin_amdgcn_global_load_lds(
      (const __attribute__((address_space(1))) unsigned int*)g,
      (__attribute__((address_space(3))) unsigned int*)l, 16, 0, 0);
}

#define CVT_BLOCKS ((MM * KK) / (256 * 8))      // 16384
#define WT_BLOCKS ((NN / 32) * (KK / 32))       // 16384

// ---------------- merged prep: X convert (bid<CVT_BLOCKS) + W transpose ----------------
template <int DO_X>
__global__ void prep_kernel(const float* __restrict__ X, ushort_t* __restrict__ XB,
                            const float* __restrict__ W, ushort_t* __restrict__ WT) {
  __shared__ float t[32][33];
  const int bid = blockIdx.x;
  const int tid = threadIdx.x;
  if (DO_X && bid < CVT_BLOCKS) {
    const size_t i = ((size_t)bid * 256 + tid) * 8;
    f32x4 v0 = __builtin_nontemporal_load(reinterpret_cast<const f32x4*>(&X[i]));
    f32x4 v1 = __builtin_nontemporal_load(reinterpret_cast<const f32x4*>(&X[i + 4]));
    short8 o;
    o[0] = (short)f2bf(v0[0]); o[1] = (short)f2bf(v0[1]);
    o[2] = (short)f2bf(v0[2]); o[3] = (short)f2bf(v0[3]);
    o[4] = (short)f2bf(v1[0]); o[5] = (short)f2bf(v1[1]);
    o[6] = (short)f2bf(v1[2]); o[7] = (short)f2bf(v1[3]);
    *reinterpret_cast<short8*>(&XB[i]) = o;
  } else {
    const int b2 = DO_X ? (bid - CVT_BLOCKS) : bid;
    const int n0 = (b2 & 127) * 32, k0 = (b2 >> 7) * 32;
    const int tx = tid & 31, ty = tid >> 5;  // 32 x 8
#pragma unroll
    for (int i = ty; i < 32; i += 8)
      t[i][tx] = __builtin_nontemporal_load(&W[(size_t)(k0 + i) * NN + n0 + tx]);
    __syncthreads();
#pragma unroll
    for (int i = ty; i < 32; i += 8)
      WT[(size_t)(n0 + i) * KK + k0 + tx] = f2bf(t[tx][i]);
  }
}

// ---------------- main fused GEMM: 256x256 tile, 8-phase counted-vmcnt schedule --------
// R11 = R9/R3 champion restored (best total 327.9/329.0 us, reproduced twice).
// Session verdict: 6 scheduling nulls (pins/clobbers/waits/reg-naming/slack)
// and 4 structural regressions (occupancy trades, hand-pipeline, direct-B,
// 32x32 shape -> bank conflicts) bracket this config as the plateau reachable
// through bench+counter iteration. 32x32 MFMA is conflict-prone under this
// swizzle family (R5/R6/R10: 2.5-3.4e7 conflicts; all 16x16 kernels: 0).
//
// Region rotation (verified):
//   reads:  A0:p1  B0:p1,p4(reload)  B1:p2  A1:p3
//   stages: p1 -> (t+1).B0 [nxt buf]; p2 -> (t+2).A0; p3 -> (t+2).B1;
//           p4 -> (t+2).A1 [all cur buf, region free after last read]
// vmcnt: 8 stage-loads/tile; vmcnt(6) at p4 retires exactly all of tile t+1.
// Prologue: t0 all regions (8 loads) + t1.{A0,B1,A1} (6) -> vmcnt(6) = t0.
#define LDSE 32768  // elements per buffer (A 16384 + B 16384)

#define STAGE_A(buf, h, kt)                                                    \
  {                                                                            \
    const int r_ = (h) * 64 + wid * 8;                                         \
    gload_lds16(XB + offA[h][0] + (kt), &lds[(buf) * LDSE + r_ * 64]);         \
    gload_lds16(XB + offA[h][1] + (kt), &lds[(buf) * LDSE + (r_ + 128) * 64]); \
  }

#define STAGE_B(buf, qn, kt)                                                   \
  {                                                                            \
    const int r_ = (qn) * 32 + (wid >> 2) * 64 + (wid & 3) * 8;                \
    gload_lds16(WT + offB[qn][0] + (kt),                                       \
                &lds[(buf) * LDSE + 16384 + r_ * 64]);                         \
    gload_lds16(WT + offB[qn][1] + (kt),                                       \
                &lds[(buf) * LDSE + 16384 + (r_ + 128) * 64]);                 \
  }

#define LOAD_A(dst, buf, qm)                                                   \
  _Pragma("unroll") for (int i = 0; i < 4; ++i) {                              \
    dst[0][i] = *reinterpret_cast<const short8*>(                              \
        &lds[(buf) * LDSE + aOff + (qm) * 4096 + i * 1024 + slot0]);           \
    dst[1][i] = *reinterpret_cast<const short8*>(                              \
        &lds[(buf) * LDSE + aOff + (qm) * 4096 + i * 1024 + slot1]);           \
  }

#define LOAD_B(dst, buf, qn)                                                   \
  _Pragma("unroll") for (int jj = 0; jj < 2; ++jj) {                           \
    dst[0][jj] = *reinterpret_cast<const short8*>(                             \
        &lds[(buf) * LDSE + bOff + (qn) * 2048 + jj * 1024 + slot0]);          \
    dst[1][jj] = *reinterpret_cast<const short8*>(                             \
        &lds[(buf) * LDSE + bOff + (qn) * 2048 + jj * 1024 + slot1]);          \
  }

#define MFMA_QUAD(AF, BF, QM, QN)                                              \
  __builtin_amdgcn_s_setprio(1);                                               \
  _Pragma("unroll") for (int ks = 0; ks < 2; ++ks)                             \
      _Pragma("unroll") for (int i = 0; i < 4; ++i)                            \
          _Pragma("unroll") for (int jj = 0; jj < 2; ++jj)                     \
              acc[(QM) * 4 + i][(QN) * 2 + jj] =                               \
      MFMA_BF16(AF[ks][i], BF[ks][jj], acc[(QM) * 4 + i][(QN) * 2 + jj], 0, 0, 0); \
  __builtin_amdgcn_s_setprio(0);

#define BAR() __builtin_amdgcn_s_barrier()

#define TILE_BODY(cur, nxt, t)                                                 \
  {                                                                            \
    const int k1 = (((t) + 1) & (NT - 1)) * BK;                                \
    const int k2 = (((t) + 2) & (NT - 1)) * BK;                                \
    /* phase 1: quadrant (0,0); stage (t+1).B0 */                              \
    LOAD_A(a, cur, 0);                                                         \
    LOAD_B(b, cur, 0);                                                         \
    STAGE_B(nxt, 0, k1);                                                       \
    BAR();                                                                     \
    MFMA_QUAD(a, b, 0, 0);                                                     \
    BAR();                                                                     \
    /* phase 2: quadrant (0,1); stage (t+2).A0 */                              \
    LOAD_B(b, cur, 1);                                                         \
    STAGE_A(cur, 0, k2);                                                       \
    BAR();                                                                     \
    MFMA_QUAD(a, b, 0, 1);                                                     \
    BAR();                                                                     \
    /* phase 3: quadrant (1,1); stage (t+2).B1 */                              \
    LOAD_A(a, cur, 1);                                                         \
    STAGE_B(cur, 1, k2);                                                       \
    BAR();                                                                     \
    MFMA_QUAD(a, b, 1, 1);                                                     \
    BAR();                                                                     \
    /* phase 4: quadrant (1,0); B0 reload; stage (t+2).A1 */                   \
    LOAD_B(b, cur, 0);                                                         \
    STAGE_A(cur, 1, k2);                                                       \
    asm volatile("s_waitcnt vmcnt(6)" ::: "memory");                           \
    BAR();                                                                     \
    MFMA_QUAD(a, b, 1, 0);                                                     \
    BAR();                                                                     \
  }

__global__ __launch_bounds__(512, 2) void gemm_bf16_256(
    const ushort_t* __restrict__ XB, const ushort_t* __restrict__ WT,
    const float* __restrict__ Y, float* __restrict__ O) {
  __shared__ ushort_t lds[2 * LDSE];  // 128 KB

  // block map: xcd = wg&7 owns n-band of 2 tiles x all 32 m-tiles, m-fastest.
  // Per-XCD B working set = 4MB = L2-resident; A shared via L3.
  const int wg = blockIdx.x;
  const int xcd = wg & 7;
  const int local = wg >> 3;                     // 0..63
  const int bm0 = (local >> 1) * 256;            // 32 m-tiles, fastest
  const int bn0 = (xcd * 2 + (local & 1)) * 256; // 2-wide n-band per XCD

  const int tid = threadIdx.x;
  const int lane = tid & 63;
  const int wid = tid >> 6;   // 0..7
  const int wmi = wid >> 2;   // 0..1 (M wave-groups, 128 rows each)
  const int wni = wid & 3;    // 0..3 (N wave-groups, 64 cols each)

  // staging lane decomposition (pre-swizzled global source slot)
  const int l8 = lane >> 3;
  const int sslot = (lane & 7) ^ l8;

  // precomputed u32 element offsets for the 8 stage streams
  uint32_t offA[2][2], offB[2][2];
#pragma unroll
  for (int h = 0; h < 2; ++h)
#pragma unroll
    for (int q = 0; q < 2; ++q) {
      const int rA = h * 64 + wid * 8 + q * 128;
      offA[h][q] = (uint32_t)(bm0 + rA + l8) * KK + sslot * 8;
      const int rB = h * 32 + (wid >> 2) * 64 + (wid & 3) * 8 + q * 128;
      offB[h][q] = (uint32_t)(bn0 + rB + l8) * KK + sslot * 8;
    }

  // fragment read decomposition
  const int lr = lane & 15, lg = lane >> 4, lr7 = lane & 7;
  const int slot0 = (lg ^ lr7) * 8;        // ks=0, elements
  const int slot1 = ((4 | lg) ^ lr7) * 8;  // ks=1
  const int aOff = (wmi * 128 + lr) * 64;          // A region row base (elems)
  const int bOff = 16384 + (wni * 64 + lr) * 64;   // B region row base

  f32x4 acc[8][4] = {};
  short8 a[2][4], b[2][2];

  // ---- prologue: t0 all regions (8 loads) + t1.{A0,B1,A1} (6 loads) ----
  STAGE_A(0, 0, 0);   // t0.A0
  STAGE_B(0, 0, 0);   // t0.B0
  STAGE_B(0, 1, 0);   // t0.B1
  STAGE_A(0, 1, 0);   // t0.A1
  STAGE_A(1, 0, BK);  // t1.A0
  STAGE_B(1, 1, BK);  // t1.B1
  STAGE_A(1, 1, BK);  // t1.A1
  asm volatile("s_waitcnt vmcnt(6)" ::: "memory");  // t0 complete
  BAR();

#pragma unroll 1
  for (int t = 0; t < NT; t += 2) {
    TILE_BODY(0, 1, t);
    TILE_BODY(1, 0, t + 1);
  }

  // epilogue: C/D layout col=lane&15, row=(lane>>4)*4+r  [m89-verified]
  // (outstanding wrapped stage loads write only LDS; final drain at endpgm)
#pragma unroll
  for (int mi = 0; mi < 8; ++mi) {
#pragma unroll
    for (int nj = 0; nj < 4; ++nj) {
#pragma unroll
      for (int r = 0; r < 4; ++r) {
        const int grow = bm0 + wmi * 128 + mi * 16 + lg * 4 + r;
        const int gcol = bn0 + wni * 64 + nj * 16 + lr;
        const size_t idx = (size_t)grow * NN + gcol;
        const float yv = __builtin_nontemporal_load(&Y[idx]);
        __builtin_nontemporal_store(epilogue(acc[mi][nj][r], yv), &O[idx]);
      }
    }
  }
}

// ---------------- mid-tier (validated R1): reg-staged conversion GEMM ----------------
#define LDP 72
__global__ __launch_bounds__(256, 3) void gemm_fused(
    const float* __restrict__ X, const ushort_t* __restrict__ WT,
    const float* __restrict__ Y, float* __restrict__ O) {
  __shared__ ushort_t Asm[BM * LDP];
  __shared__ ushort_t Bsm[BN * LDP];

  const int nwg = (MM / BM) * (NN / BN);
  int wg = blockIdx.x;
  wg = (wg % 8) * (nwg / 8) + wg / 8;
  const int NTC = NN / BN;
  const int bm0 = (wg / NTC) * BM;
  const int bn0 = (wg % NTC) * BN;

  const int tid = threadIdx.x;
  const int lane = tid & 63;
  const int wid = tid >> 6;
  const int wm = (wid >> 1) * 64, wn = (wid & 1) * 64;
  const int lr = lane & 15, lg = lane >> 4;

  f32x4 acc[4][4] = {};

  const int arow = tid >> 2;
  const int ac = (tid & 3) * 4;
  const int brow = tid >> 1;
  const int bc0 = (tid & 1) * 32;

  for (int kt = 0; kt < KK; kt += BK) {
    __syncthreads();
#pragma unroll
    for (int p = 0; p < 2; ++p) {
      const int row = arow + p * 64;
      const float* src = &X[(size_t)(bm0 + row) * KK + kt];
#pragma unroll
      for (int j = 0; j < 4; ++j) {
        f32x4 v = *reinterpret_cast<const f32x4*>(&src[ac + j * 16]);
        uint2 packed;
        packed.x = (uint32_t)f2bf(v[0]) | ((uint32_t)f2bf(v[1]) << 16);
        packed.y = (uint32_t)f2bf(v[2]) | ((uint32_t)f2bf(v[3]) << 16);
        *reinterpret_cast<uint2*>(&Asm[row * LDP + ac + j * 16]) = packed;
      }
    }
    {
      const ushort_t* src = &WT[(size_t)(bn0 + brow) * KK + kt + bc0];
#pragma unroll
      for (int j = 0; j < 4; ++j) {
        short8 u = *reinterpret_cast<const short8*>(&src[j * 8]);
        *reinterpret_cast<short8*>(&Bsm[brow * LDP + bc0 + j * 8]) = u;
      }
    }
    __syncthreads();

#pragma unroll
    for (int ks = 0; ks < 2; ++ks) {
      short8 a[4], b[4];
#pragma unroll
      for (int i = 0; i < 4; ++i) {
        a[i] = *reinterpret_cast<const short8*>(&Asm[(wm + i * 16 + lr) * LDP + ks * 32 + lg * 8]);
        b[i] = *reinterpret_cast<const short8*>(&Bsm[(wn + i * 16 + lr) * LDP + ks * 32 + lg * 8]);
      }
#pragma unroll
      for (int i = 0; i < 4; ++i)
#pragma unroll
        for (int j = 0; j < 4; ++j)
          acc[i][j] = MFMA_BF16(a[i], b[j], acc[i][j], 0, 0, 0);
    }
  }

#pragma unroll
  for (int i = 0; i < 4; ++i) {
#pragma unroll
    for (int j = 0; j < 4; ++j) {
#pragma unroll
      for (int r = 0; r < 4; ++r) {
        const int grow = bm0 + wm + i * 16 + lg * 4 + r;
        const int gcol = bn0 + wn + j * 16 + lr;
        const size_t idx = (size_t)grow * NN + gcol;
        O[idx] = epilogue(acc[i][j][r], Y[idx]);
      }
    }
  }
}

// ---------------- naive fallback ----------------
__global__ void naive_fused(const float* __restrict__ X, const float* __restrict__ W,
                            const float* __restrict__ Y, float* __restrict__ O) {
  const int n0 = (blockIdx.x * 256 + threadIdx.x) * 4;
  const int m = blockIdx.y;
  f32x4 acc = {0.f, 0.f, 0.f, 0.f};
  const float* xr = &X[(size_t)m * KK];
  for (int k = 0; k < KK; ++k) {
    const float xv = xr[k];
    const f32x4 wv = *reinterpret_cast<const f32x4*>(&W[(size_t)k * NN + n0]);
    acc[0] += xv * wv[0];
    acc[1] += xv * wv[1];
    acc[2] += xv * wv[2];
    acc[3] += xv * wv[3];
  }
  const size_t idx = (size_t)m * NN + n0;
  O[idx + 0] = epilogue(acc[0], Y[idx + 0]);
  O[idx + 1] = epilogue(acc[1], Y[idx + 1]);
  O[idx + 2] = epilogue(acc[2], Y[idx + 2]);
  O[idx + 3] = epilogue(acc[3], Y[idx + 3]);
}

extern "C" void kernel_launch(void* const* d_in, const int* in_sizes, int n_in,
                              void* d_out, int out_size, void* d_ws, size_t ws_size,
                              hipStream_t stream) {
  const float* x = (const float*)d_in[0];
  const float* y = (const float*)d_in[1];
  const float* w = (const float*)d_in[2];
  float* out = (float*)d_out;

  const size_t xb_bytes = (size_t)MM * KK * sizeof(ushort_t);  // 67.1 MB
  const size_t wt_bytes = (size_t)NN * KK * sizeof(ushort_t);  // 33.5 MB

  if (ws_size >= xb_bytes + wt_bytes) {
    ushort_t* XB = (ushort_t*)d_ws;
    ushort_t* WT = (ushort_t*)((char*)d_ws + xb_bytes);
    hipLaunchKernelGGL((prep_kernel<1>), dim3(CVT_BLOCKS + WT_BLOCKS), dim3(256), 0, stream,
                       x, XB, w, WT);
    hipLaunchKernelGGL(gemm_bf16_256, dim3((MM / 256) * (NN / 256)), dim3(512), 0, stream,
                       XB, WT, y, out);
  } else if (ws_size >= wt_bytes) {
    ushort_t* WT = (ushort_t*)d_ws;
    hipLaunchKernelGGL((prep_kernel<0>), dim3(WT_BLOCKS), dim3(256), 0, stream,
                       x, nullptr, w, WT);
    hipLaunchKernelGGL(gemm_fused, dim3((MM / BM) * (NN / BN)), dim3(256), 0, stream,
                       x, WT, y, out);
  } else {
    hipLaunchKernelGGL(naive_fused, dim3(NN / 1024, MM), dim3(256), 0, stream, x, w, y, out);
  }
}